// Round 10
// baseline (326.993 us; speedup 1.0000x reference)
//
#include <hip/hip_runtime.h>

#define N_NODES 100000
#define N_EDGES 1600000
#define NPB 32                       // nodes per bucket (dst >> 5)
#define NB (N_NODES / NPB)           // 3125 buckets
#define CAP 704                      // slots per bucket (mean 512 + 8.5 sigma)
#define NCC 49                       // coarse cells (dst >> 11)
#define CAPA 34816                   // slots per coarse cell (mean 32768 + 11 sigma)
#define NFB 64                       // fine buckets per coarse cell
#define BPC 16                       // blocks per cell in pass B
#define N16 (N_NODES * 16)           // elements per half-table (16 cols/node)
#define GHB 6250                     // node-blocks per half-pass (6250*16 = 100000)
#define M1W 50000                    // mask1 u64 words (N*32/64)
#define M2W 100000                   // mask2 u64 words (N*64/64)

typedef float v2f __attribute__((ext_vector_type(2)));

// Opaque register pin (kept for k_transform1 — that kernel is verified <47us)
#define PIN4(v) asm volatile("" : "+v"(v.x), "+v"(v.y), "+v"(v.z), "+v"(v.w))

// ---------------- JAX threefry2x32 (partitionable scheme) ----------------
struct U2 { unsigned a, b; };

__host__ __device__ constexpr U2 tf2x32(unsigned k0, unsigned k1, unsigned c0, unsigned c1) {
  unsigned ks2 = k0 ^ k1 ^ 0x1BD11BDAu;
  unsigned x0 = c0 + k0, x1 = c1 + k1;
#define TFR(r) { x0 += x1; x1 = (x1 << (r)) | (x1 >> (32 - (r))); x1 ^= x0; }
  TFR(13) TFR(15) TFR(26) TFR(6)
  x0 += k1;  x1 += ks2 + 1u;
  TFR(17) TFR(29) TFR(16) TFR(24)
  x0 += ks2; x1 += k0 + 2u;
  TFR(13) TFR(15) TFR(26) TFR(6)
  x0 += k0;  x1 += k1 + 3u;
  TFR(17) TFR(29) TFR(16) TFR(24)
  x0 += k1;  x1 += ks2 + 4u;
  TFR(13) TFR(15) TFR(26) TFR(6)
  x0 += ks2; x1 += k0 + 5u;
#undef TFR
  return U2{x0, x1};
}

constexpr U2 DK0 = tf2x32(0u, 42u, 0u, 0u);
constexpr U2 DK1 = tf2x32(0u, 42u, 0u, 1u);

__device__ __forceinline__ bool keep_bit(unsigned k0, unsigned k1, unsigned j) {
  U2 w = tf2x32(k0, k1, 0u, j);
  return ((w.a ^ w.b) >> 31) == 0u;
}

// bf16 storage helpers (RNE pack, shift unpack)
__device__ __forceinline__ unsigned short f2bf(float f) {
  unsigned u = __float_as_uint(f);
  u += 0x7FFFu + ((u >> 16) & 1u);
  return (unsigned short)(u >> 16);
}
// unpack uint32 (2 bf16) -> v2f
__device__ __forceinline__ v2f up2(unsigned r) {
  v2f v;
  v.x = __uint_as_float(r << 16);
  v.y = __uint_as_float(r & 0xFFFF0000u);
  return v;
}

// weight column quad: W[(4i..4i+3)][lane] with leading dim ld (i literal)
__device__ __forceinline__ float4 ldcol(const float* __restrict__ W, int i,
                                        int lane, int ld) {
  float4 v;
  v.x = W[(i * 4 + 0) * ld + lane];
  v.y = W[(i * 4 + 1) * ld + lane];
  v.z = W[(i * 4 + 2) * ld + lane];
  v.w = W[(i * 4 + 3) * ld + lane];
  return v;
}

// ------ Mask precompute + W2 transposes ----------------------------------
// Blocks 2..3 write the transposed W2 tables (col-contiguous, 16 KB) used
// by the per-thread k_out2 (wave-uniform s_load path, verified round 5).
__global__ __launch_bounds__(256) void k_mask(
    unsigned long long* __restrict__ msk,
    const float* __restrict__ W2l, const float* __restrict__ W2r,
    float* __restrict__ wt) {
  int bid = blockIdx.x, tid = threadIdx.x;
  if (bid == 2) {
    for (int i = tid; i < 2048; i += 256) { int c = i >> 5, k = i & 31; wt[i] = W2l[k * 64 + c]; }
  } else if (bid == 3) {
    for (int i = tid; i < 2048; i += 256) { int c = i >> 5, k = i & 31; wt[2048 + i] = W2r[k * 64 + c]; }
  }
  int w = (int)((blockIdx.x * blockDim.x + threadIdx.x) >> 6);
  int lane = threadIdx.x & 63;
  int nw = (int)((gridDim.x * blockDim.x) >> 6);
  for (; w < M1W + M2W; w += nw) {
    unsigned k0, k1, j;
    if (w < M1W) { k0 = DK0.a; k1 = DK0.b; j = (unsigned)w * 64u + (unsigned)lane; }
    else { k0 = DK1.a; k1 = DK1.b; j = (unsigned)(w - M1W) * 64u + (unsigned)lane; }
    unsigned long long bits = __ballot(keep_bit(k0, k1, j));
    if (lane == 0) msk[w] = bits;
  }
}

// ------ Kernel A: xl = bf16(x@W1_l) into 2 half-tables, xr = x@W1_r ------
// Wave-per-node persistent; weight column PINNED; dbuf LDS staging.
// (round-8 verified lineage, < 47 us — untouched)
__global__ __launch_bounds__(256, 4) void k_transform1(
    const float* __restrict__ x, const float* __restrict__ Wl,
    const float* __restrict__ Wr, unsigned short* __restrict__ xlbh,
    float* __restrict__ xr) {
  __shared__ __align__(16) float rv[2][4][64];
  int lane = threadIdx.x & 63;
  int wv = (threadIdx.x >> 6) & 3;
  const float* W = (lane < 32) ? Wl : Wr;
  int c = lane & 31;
  float4 V0 = ldcol(W, 0, c, 32);   PIN4(V0);
  float4 V1 = ldcol(W, 1, c, 32);   PIN4(V1);
  float4 V2 = ldcol(W, 2, c, 32);   PIN4(V2);
  float4 V3 = ldcol(W, 3, c, 32);   PIN4(V3);
  float4 V4 = ldcol(W, 4, c, 32);   PIN4(V4);
  float4 V5 = ldcol(W, 5, c, 32);   PIN4(V5);
  float4 V6 = ldcol(W, 6, c, 32);   PIN4(V6);
  float4 V7 = ldcol(W, 7, c, 32);   PIN4(V7);
  float4 V8 = ldcol(W, 8, c, 32);   PIN4(V8);
  float4 V9 = ldcol(W, 9, c, 32);   PIN4(V9);
  float4 V10 = ldcol(W, 10, c, 32); PIN4(V10);
  float4 V11 = ldcol(W, 11, c, 32); PIN4(V11);
  float4 V12 = ldcol(W, 12, c, 32); PIN4(V12);
  float4 V13 = ldcol(W, 13, c, 32); PIN4(V13);
  float4 V14 = ldcol(W, 14, c, 32); PIN4(V14);
  float4 V15 = ldcol(W, 15, c, 32); PIN4(V15);
  int wid0 = (int)((blockIdx.x * blockDim.x + threadIdx.x) >> 6);
  int wstride = (int)((gridDim.x * blockDim.x) >> 6);
  float xv = x[wid0 * 64 + lane];      // prologue prefetch
  int b = 0;
  for (int wid = wid0; wid < N_NODES; wid += wstride) {
    rv[b][wv][lane] = xv;              // staged row
    int nxt = wid + wstride;
    if (nxt < N_NODES) xv = x[nxt * 64 + lane];   // prefetch under GEMM
    asm volatile("s_waitcnt lgkmcnt(0)" ::: "memory");   // same-wave LDS drain
    const float* rb = &rv[b][wv][0];
    v2f s0 = {0.f, 0.f}, s1 = {0.f, 0.f};
#define TST(Vi, i) { \
    float4 r = *(const float4*)(rb + (i) * 4); \
    v2f w0; w0.x = Vi.x; w0.y = Vi.y; \
    v2f w1; w1.x = Vi.z; w1.y = Vi.w; \
    v2f p0; p0.x = r.x; p0.y = r.y; \
    v2f p1; p1.x = r.z; p1.y = r.w; \
    s0 += p0 * w0; s1 += p1 * w1; }
    TST(V0, 0)  TST(V1, 1)  TST(V2, 2)  TST(V3, 3)
    TST(V4, 4)  TST(V5, 5)  TST(V6, 6)  TST(V7, 7)
    TST(V8, 8)  TST(V9, 9)  TST(V10, 10) TST(V11, 11)
    TST(V12, 12) TST(V13, 13) TST(V14, 14) TST(V15, 15)
#undef TST
    float s = (s0.x + s0.y) + (s1.x + s1.y);
    if (lane < 32) xlbh[(size_t)(c >> 4) * N16 + wid * 16 + (c & 15)] = f2bf(s);
    else           xr[wid * 32 + c] = s;
    b ^= 1;
  }
}

// ------ Pass A: LDS-staged partition by coarse cell (dst>>11), 49 cells ---
__global__ __launch_bounds__(256) void k_binA(
    const int* __restrict__ src, const int* __restrict__ dst,
    int* __restrict__ curA, unsigned* __restrict__ bufA) {
  __shared__ int hist[NCC];
  __shared__ int offsL[NCC + 1];
  __shared__ int baseL[NCC];
  __shared__ int place[NCC];
  __shared__ unsigned stag[2048];
  __shared__ unsigned char cellb[2048];
  int t = threadIdx.x;
  for (long long start = (long long)blockIdx.x * 2048; start < N_EDGES;
       start += (long long)gridDim.x * 2048) {
    int n = (int)min((long long)2048, (long long)N_EDGES - start);
    for (int i = t; i < NCC; i += 256) hist[i] = 0;
    __syncthreads();
    unsigned pv[8]; int pc[8];
#pragma unroll
    for (int i = 0; i < 8; ++i) {
      int idx = t + i * 256;
      if (idx < n) {
        int d = dst[start + idx];
        int s = src[start + idx];
        int cc = d >> 11;
        pc[i] = cc;
        pv[i] = (unsigned)s | ((unsigned)(d & 2047) << 17);
        atomicAdd(&hist[cc], 1);
      } else pc[i] = -1;
    }
    __syncthreads();
    if (t < 64) {
      int lane = t;
      int v = (lane < NCC) ? hist[lane] : 0;
      int x = v;
#pragma unroll
      for (int o = 1; o < 64; o <<= 1) {
        int y = __shfl_up(x, o, 64);
        if (lane >= o) x += y;
      }
      if (lane < NCC) {
        offsL[lane] = x - v;
        place[lane] = 0;
        if (v > 0) baseL[lane] = atomicAdd(&curA[lane], v);
      }
      if (lane == NCC - 1) offsL[NCC] = x;
    }
    __syncthreads();
#pragma unroll
    for (int i = 0; i < 8; ++i) {
      if (pc[i] >= 0) {
        int p = atomicAdd(&place[pc[i]], 1);
        int sl = offsL[pc[i]] + p;
        stag[sl] = pv[i];
        cellb[sl] = (unsigned char)pc[i];
      }
    }
    __syncthreads();
    for (int s2 = t; s2 < n; s2 += 256) {     // coalesced copy-out, no search
      int cell = cellb[s2];
      int pos = baseL[cell] + (s2 - offsL[cell]);
      if (pos < CAPA) bufA[(size_t)cell * CAPA + pos] = stag[s2];
    }
    __syncthreads();
  }
}

// ------ Pass B: refine each coarse cell into 64 fine buckets -------------
__global__ __launch_bounds__(256) void k_binB(
    const unsigned* __restrict__ bufA, const int* __restrict__ curA,
    int* __restrict__ cur, unsigned* __restrict__ buf) {
  __shared__ int hist[NFB];
  __shared__ int offsL[NFB + 1];
  __shared__ int baseL[NFB];
  __shared__ int place[NFB];
  __shared__ unsigned stag[2048];
  __shared__ unsigned char cellb[2048];
  int cellc = blockIdx.x / BPC;
  int slice = blockIdx.x % BPC;
  int t = threadIdx.x;
  int cnt = min(curA[cellc], CAPA);
  const unsigned* in = bufA + (size_t)cellc * CAPA;
  for (int start = slice * 2048; start < cnt; start += BPC * 2048) {
    int n = min(2048, cnt - start);
    for (int i = t; i < NFB; i += 256) hist[i] = 0;
    __syncthreads();
    unsigned pv[8]; int pb[8];
#pragma unroll
    for (int i = 0; i < 8; ++i) {
      int idx = t + i * 256;
      if (idx < n) {
        unsigned w = in[start + idx];
        int dlow = (int)(w >> 17);
        int fb = dlow >> 5;
        pb[i] = fb;
        pv[i] = (w & 0x1FFFFu) | ((unsigned)(dlow & 31) << 17);
        atomicAdd(&hist[fb], 1);
      } else pb[i] = -1;
    }
    __syncthreads();
    if (t < 64) {
      int lane = t;
      int v = hist[lane];
      int x = v;
#pragma unroll
      for (int o = 1; o < 64; o <<= 1) {
        int y = __shfl_up(x, o, 64);
        if (lane >= o) x += y;
      }
      offsL[lane] = x - v;
      place[lane] = 0;
      if (v > 0) baseL[lane] = atomicAdd(&cur[cellc * NFB + lane], v);
      if (lane == 63) offsL[NFB] = x;
    }
    __syncthreads();
#pragma unroll
    for (int i = 0; i < 8; ++i) {
      if (pb[i] >= 0) {
        int p = atomicAdd(&place[pb[i]], 1);
        int sl = offsL[pb[i]] + p;
        stag[sl] = pv[i];
        cellb[sl] = (unsigned char)pb[i];
      }
    }
    __syncthreads();
    for (int s2 = t; s2 < n; s2 += 256) {
      int fb = cellb[s2];
      int pos = baseL[fb] + (s2 - offsL[fb]);
      if (pos < CAP) buf[(size_t)(cellc * NFB + fb) * CAP + pos] = stag[s2];
    }
    __syncthreads();
  }
}

// --------- single-block exclusive scan of bucket totals -> bbase ----------
__global__ __launch_bounds__(1024) void k_bscan(
    const int* __restrict__ cur, int* __restrict__ bbase) {
  __shared__ int warp_sums[16];
  __shared__ int s_running;
  int t = threadIdx.x;
  int lane = t & 63, w = t >> 6;
  if (t == 0) s_running = 0;
  __syncthreads();
  for (int base = 0; base < NB; base += 1024) {
    int i = base + t;
    int v = (i < NB) ? min(cur[i], CAP) : 0;
    int x = v;
#pragma unroll
    for (int o = 1; o < 64; o <<= 1) {
      int y = __shfl_up(x, o, 64);
      if (lane >= o) x += y;
    }
    if (lane == 63) warp_sums[w] = x;
    __syncthreads();
    if (w == 0) {
      int ws = (lane < 16) ? warp_sums[lane] : 0;
#pragma unroll
      for (int o = 1; o < 16; o <<= 1) {
        int y = __shfl_up(ws, o, 64);
        if (lane >= o) ws += y;
      }
      if (lane < 16) warp_sums[lane] = ws;
    }
    __syncthreads();
    int incl = x + (w > 0 ? warp_sums[w - 1] : 0);
    int excl = s_running + incl - v;
    if (i < NB) bbase[i] = excl;
    __syncthreads();
    if (t == 1023) s_running += incl;
    __syncthreads();
  }
}

// ------ block per bucket: LDS-staged count + prefix, dense CSR fill -------
__global__ __launch_bounds__(256) void k_bfill(
    const unsigned* __restrict__ buf, const int* __restrict__ cur,
    const int* __restrict__ bbase, int* __restrict__ deg,
    int* __restrict__ offs, int* __restrict__ eidx) {
  __shared__ int ncnt[NPB];
  __shared__ int ncur[NPB];
  __shared__ unsigned sbuf[CAP];
  int b = blockIdx.x, t = threadIdx.x;
  if (t < NPB) ncnt[t] = 0;
  __syncthreads();
  int nb = min(cur[b], CAP);
  const unsigned* bb = buf + (size_t)b * CAP;
  for (int slot = t; slot < nb; slot += 256) {
    unsigned w = bb[slot];
    sbuf[slot] = w;
    atomicAdd(&ncnt[w >> 17], 1);
  }
  __syncthreads();
  if (t < 64) {
    int lane = t;
    int c = (lane < NPB) ? ncnt[lane] : 0;
    int x = c;
#pragma unroll
    for (int o = 1; o < 32; o <<= 1) {
      int y = __shfl_up(x, o, 64);
      if (lane >= o) x += y;
    }
    if (lane < NPB) {
      int excl = x - c;
      ncur[lane] = excl;
      int gn = b * NPB + lane;
      deg[gn] = c;
      offs[gn] = bbase[b] + excl;
    }
  }
  __syncthreads();
  int base = bbase[b];
  for (int slot = t; slot < nb; slot += 256) {
    unsigned w = sbuf[slot];
    int p = atomicAdd(&ncur[w >> 17], 1);
    eidx[base + p] = (int)(w & 0x1FFFF);
  }
}

// ---- Gather layer 1, half-column pass: 4 nodes/wave, 16 lanes/node ------
__global__ __launch_bounds__(256) void k_gather1(
    const unsigned short* __restrict__ xlbh, const float* __restrict__ xr,
    const int* __restrict__ offs, const int* __restrict__ deg,
    const int* __restrict__ eidx, const float* __restrict__ b1,
    const unsigned long long* __restrict__ msk1,
    unsigned short* __restrict__ hpbh) {
  int bb = blockIdx.x;
  int G = 0, nb = bb;
  if (nb >= GHB) { G = 1; nb -= GHB; }
  int tid = threadIdx.x;
  int lane = tid & 63;
  int node = nb * 16 + (tid >> 4);     // 16 nodes per block (6250*16 = 100000)
  int g = (tid >> 2) & 3;              // edge group within quarter
  int ch = tid & 3;                    // uint2 chunk of half-row
  int c = tid & 15;                    // column within half
  int col = G * 16 + c;
  int off = offs[node];
  int dg = deg[node];
  float xr_v = xr[node * 32 + col];    // hoisted, in flight during gather
  float b1_v = b1[col];
  unsigned jj = (unsigned)(node * 32 + col);
  unsigned long long mw = msk1[jj >> 6];   // hoisted mask word (L2 hit)
  const uint2* H = (const uint2*)(xlbh + (size_t)G * N16);
  v2f acc01 = {0.f, 0.f}, acc23 = {0.f, 0.f};
  int k = 0;
  for (; k + 8 <= dg; k += 8) {        // 8 edges/node/iter
    int s0 = eidx[off + k + g];
    int s1 = eidx[off + k + 4 + g];
    uint2 r0 = H[s0 * 4 + ch];
    uint2 r1 = H[s1 * 4 + ch];
    acc01 += up2(r0.x); acc23 += up2(r0.y);
    acc01 += up2(r1.x); acc23 += up2(r1.y);
  }
  for (; k < dg; k += 4) {
    if (k + g < dg) {
      int s = eidx[off + k + g];
      uint2 r = H[s * 4 + ch];
      acc01 += up2(r.x); acc23 += up2(r.y);
    }
  }
  float a0 = acc01.x, a1 = acc01.y, a2 = acc23.x, a3 = acc23.y;
  // reduce across the 4 groups (lane bits 2,3) — intra-quarter
  a0 += __shfl_xor(a0, 4, 64); a0 += __shfl_xor(a0, 8, 64);
  a1 += __shfl_xor(a1, 4, 64); a1 += __shfl_xor(a1, 8, 64);
  a2 += __shfl_xor(a2, 4, 64); a2 += __shfl_xor(a2, 8, 64);
  a3 += __shfl_xor(a3, 4, 64); a3 += __shfl_xor(a3, 8, 64);
  // redistribute: lane wants col c; source lane = quarter_base + (c>>2)
  int srcl = (lane & 48) + (c >> 2);
  float t0 = __shfl(a0, srcl, 64);
  float t1 = __shfl(a1, srcl, 64);
  float t2 = __shfl(a2, srcl, 64);
  float t3 = __shfl(a3, srcl, 64);
  int sub = lane & 3;
  float val = (sub == 0) ? t0 : (sub == 1) ? t1 : (sub == 2) ? t2 : t3;
  float inv = 1.0f / fmaxf((float)dg, 1.0f);
  float v = val * inv + b1_v + xr_v;
  v = (v > 0.f) ? v : 0.01f * v;
  float h = ((mw >> (jj & 63)) & 1ull) ? 2.0f * v : 0.0f;
  hpbh[(size_t)G * N16 + node * 16 + c] = f2bf(h);   // contiguous 128B/wave
}

// ---- Gather layer 2, half-column pass: mean-agg of hpb half-rows --------
__global__ __launch_bounds__(256) void k_gather2(
    const unsigned short* __restrict__ hpbh, const int* __restrict__ offs,
    const int* __restrict__ deg, const int* __restrict__ eidx,
    float* __restrict__ aggh) {
  int bb = blockIdx.x;
  int G = 0, nb = bb;
  if (nb >= GHB) { G = 1; nb -= GHB; }
  int tid = threadIdx.x;
  int lane = tid & 63;
  int node = nb * 16 + (tid >> 4);
  int g = (tid >> 2) & 3;
  int ch = tid & 3;
  int c = tid & 15;
  int off = offs[node];
  int dg = deg[node];
  const uint2* H = (const uint2*)(hpbh + (size_t)G * N16);
  v2f acc01 = {0.f, 0.f}, acc23 = {0.f, 0.f};
  int k = 0;
  for (; k + 8 <= dg; k += 8) {
    int s0 = eidx[off + k + g];
    int s1 = eidx[off + k + 4 + g];
    uint2 r0 = H[s0 * 4 + ch];
    uint2 r1 = H[s1 * 4 + ch];
    acc01 += up2(r0.x); acc23 += up2(r0.y);
    acc01 += up2(r1.x); acc23 += up2(r1.y);
  }
  for (; k < dg; k += 4) {
    if (k + g < dg) {
      int s = eidx[off + k + g];
      uint2 r = H[s * 4 + ch];
      acc01 += up2(r.x); acc23 += up2(r.y);
    }
  }
  float a0 = acc01.x, a1 = acc01.y, a2 = acc23.x, a3 = acc23.y;
  a0 += __shfl_xor(a0, 4, 64); a0 += __shfl_xor(a0, 8, 64);
  a1 += __shfl_xor(a1, 4, 64); a1 += __shfl_xor(a1, 8, 64);
  a2 += __shfl_xor(a2, 4, 64); a2 += __shfl_xor(a2, 8, 64);
  a3 += __shfl_xor(a3, 4, 64); a3 += __shfl_xor(a3, 8, 64);
  int srcl = (lane & 48) + (c >> 2);
  float t0 = __shfl(a0, srcl, 64);
  float t1 = __shfl(a1, srcl, 64);
  float t2 = __shfl(a2, srcl, 64);
  float t3 = __shfl(a3, srcl, 64);
  int sub = lane & 3;
  float val = (sub == 0) ? t0 : (sub == 1) ? t1 : (sub == 2) ? t2 : t3;
  float inv = 1.0f / fmaxf((float)dg, 1.0f);
  aggh[(size_t)G * N16 + node * 16 + c] = val * inv;  // contiguous 256B/wave
}

// ---- Final: one THREAD per node, NAMED float4 regs only (no arrays,
//      no punning -> no scratch; rule #20). Weights via wave-uniform
//      s_load from transposed tables. Two-pass over columns (pass 1: ss,
//      pass 2: recompute identical FP sequence + scaled float4 store).
//      No LDS, no shuffles -> removes the 16 ds_read_b128/node floor
//      (~31 us) that capped the wave-per-node design at ~48 us. ----
__global__ __launch_bounds__(256, 4) void k_out2(
    const unsigned short* __restrict__ hpbh, const float* __restrict__ aggh,
    const float* __restrict__ W2lT, const float* __restrict__ b2,
    const float* __restrict__ W2rT, const unsigned long long* __restrict__ msk2,
    float* __restrict__ out) {
  int node = blockIdx.x * 256 + threadIdx.x;
  if (node >= N_NODES) return;
  const float4* a0p = (const float4*)(aggh + (size_t)node * 16);
  const float4* a1p = (const float4*)(aggh + (size_t)N16 + (size_t)node * 16);
  float4 A0 = a0p[0], A1 = a0p[1], A2 = a0p[2], A3 = a0p[3];
  float4 A4 = a1p[0], A5 = a1p[1], A6 = a1p[2], A7 = a1p[3];
  const uint4* h0p = (const uint4*)(hpbh + (size_t)node * 16);
  const uint4* h1p = (const uint4*)(hpbh + (size_t)N16 + (size_t)node * 16);
  uint4 ua = h0p[0], ub = h0p[1], uc = h1p[0], ud = h1p[1];
  float4 H0, H1, H2, H3, H4, H5, H6, H7;
  { v2f t0 = up2(ua.x), t1 = up2(ua.y); H0 = make_float4(t0.x, t0.y, t1.x, t1.y); }
  { v2f t0 = up2(ua.z), t1 = up2(ua.w); H1 = make_float4(t0.x, t0.y, t1.x, t1.y); }
  { v2f t0 = up2(ub.x), t1 = up2(ub.y); H2 = make_float4(t0.x, t0.y, t1.x, t1.y); }
  { v2f t0 = up2(ub.z), t1 = up2(ub.w); H3 = make_float4(t0.x, t0.y, t1.x, t1.y); }
  { v2f t0 = up2(uc.x), t1 = up2(uc.y); H4 = make_float4(t0.x, t0.y, t1.x, t1.y); }
  { v2f t0 = up2(uc.z), t1 = up2(uc.w); H5 = make_float4(t0.x, t0.y, t1.x, t1.y); }
  { v2f t0 = up2(ud.x), t1 = up2(ud.y); H6 = make_float4(t0.x, t0.y, t1.x, t1.y); }
  { v2f t0 = up2(ud.z), t1 = up2(ud.w); H7 = make_float4(t0.x, t0.y, t1.x, t1.y); }
  unsigned long long mw = msk2[node];

  // one output column: uniform weight loads (s_load) + static 64-FMA dot
#define COL(J, DD) \
  float DD; { \
    const float4* wlp = (const float4*)(W2lT + (size_t)(J) * 32); \
    const float4* wrp = (const float4*)(W2rT + (size_t)(J) * 32); \
    float4 w0 = wlp[0], w1 = wlp[1], w2 = wlp[2], w3 = wlp[3]; \
    float4 w4 = wlp[4], w5 = wlp[5], w6 = wlp[6], w7 = wlp[7]; \
    float4 u0 = wrp[0], u1 = wrp[1], u2 = wrp[2], u3 = wrp[3]; \
    float4 u4 = wrp[4], u5 = wrp[5], u6 = wrp[6], u7 = wrp[7]; \
    float s = b2[J]; \
    s += A0.x * w0.x + A0.y * w0.y + A0.z * w0.z + A0.w * w0.w; \
    s += A1.x * w1.x + A1.y * w1.y + A1.z * w1.z + A1.w * w1.w; \
    s += A2.x * w2.x + A2.y * w2.y + A2.z * w2.z + A2.w * w2.w; \
    s += A3.x * w3.x + A3.y * w3.y + A3.z * w3.z + A3.w * w3.w; \
    s += A4.x * w4.x + A4.y * w4.y + A4.z * w4.z + A4.w * w4.w; \
    s += A5.x * w5.x + A5.y * w5.y + A5.z * w5.z + A5.w * w5.w; \
    s += A6.x * w6.x + A6.y * w6.y + A6.z * w6.z + A6.w * w6.w; \
    s += A7.x * w7.x + A7.y * w7.y + A7.z * w7.z + A7.w * w7.w; \
    s += H0.x * u0.x + H0.y * u0.y + H0.z * u0.z + H0.w * u0.w; \
    s += H1.x * u1.x + H1.y * u1.y + H1.z * u1.z + H1.w * u1.w; \
    s += H2.x * u2.x + H2.y * u2.y + H2.z * u2.z + H2.w * u2.w; \
    s += H3.x * u3.x + H3.y * u3.y + H3.z * u3.z + H3.w * u3.w; \
    s += H4.x * u4.x + H4.y * u4.y + H4.z * u4.z + H4.w * u4.w; \
    s += H5.x * u5.x + H5.y * u5.y + H5.z * u5.z + H5.w * u5.w; \
    s += H6.x * u6.x + H6.y * u6.y + H6.z * u6.z + H6.w * u6.w; \
    s += H7.x * u7.x + H7.y * u7.y + H7.z * u7.z + H7.w * u7.w; \
    DD = ((mw >> (J)) & 1ull) ? 2.0f * s : 0.0f; \
  }

  // pass 1: sum of squares only (no d[64] array -> no spill)
  float ss = 0.f;
  for (int j = 0; j < 64; ++j) {
    COL(j, dd);
    ss += dd * dd;
  }
  float scale = 1.0f / fmaxf(sqrtf(ss), 1e-12f);
  // pass 2: recompute (identical FP sequence), scaled float4 stores
  float4* op = (float4*)(out + (size_t)node * 64);
  for (int j4 = 0; j4 < 16; ++j4) {
    int j = j4 * 4;
    COL(j + 0, d0);
    COL(j + 1, d1);
    COL(j + 2, d2);
    COL(j + 3, d3);
    op[j4] = make_float4(d0 * scale, d1 * scale, d2 * scale, d3 * scale);
  }
#undef COL
}

// --------------------------------------------------------------------------
extern "C" void kernel_launch(void* const* d_in, const int* in_sizes, int n_in,
                              void* d_out, int out_size, void* d_ws, size_t ws_size,
                              hipStream_t stream) {
  const float* x   = (const float*)d_in[0];
  const int*   ei  = (const int*)d_in[1];
  const float* W1l = (const float*)d_in[2];
  const float* b1  = (const float*)d_in[3];
  const float* W1r = (const float*)d_in[4];
  const float* W2l = (const float*)d_in[5];
  const float* b2  = (const float*)d_in[6];
  const float* W2r = (const float*)d_in[7];
  float* out = (float*)d_out;

  const int* src = ei;            // edge_index[0]
  const int* dst = ei + N_EDGES;  // edge_index[1]

  const size_t F32 = (size_t)N_NODES * 32;
  char* w = (char*)d_ws;
  // region 1 (12.8 MB): bufA (binning) -> xr (transform/gather1) -> aggh (gather2/out2)
  unsigned* bufA = (unsigned*)w;                 // 49*34816*4 = 6.8 MB
  float* xr      = (float*)w;                    // 12.8 MB (bufA dead by then)
  float* aggh    = (float*)w;                    // 12.8 MB (xr dead after gather1)
  w += F32 * sizeof(float);
  // region 2 (12.8 MB): buf (binning) -> xlbh[2] + hpbh[2] half-tables
  unsigned* buf  = (unsigned*)w;                 // 3125*704*4 = 8.8 MB
  unsigned short* xlbh = (unsigned short*)w;     // 2 x 3.2 MB
  unsigned short* hpbh = xlbh + 2 * (size_t)N16; // 2 x 3.2 MB (buf dead by then)
  w += F32 * 2 * sizeof(unsigned short);
  int* curA  = (int*)w; w += NCC * sizeof(int);
  int* cur   = (int*)w; w += NB * sizeof(int);
  int* bbase = (int*)w; w += NB * sizeof(int);
  int* deg   = (int*)w; w += N_NODES * sizeof(int);
  int* offs  = (int*)w; w += N_NODES * sizeof(int);
  int* eidx  = (int*)w; w += (size_t)N_EDGES * sizeof(int);   // 6.4 MB (dense)
  unsigned long long* msk = (unsigned long long*)w;           // 1.2 MB masks
  w += (size_t)(M1W + M2W) * sizeof(unsigned long long);
  float* wt = (float*)w;                                      // 16 KB transposed W2
  float* W2lT = wt;
  float* W2rT = wt + 2048;

  hipMemsetAsync(curA, 0, (size_t)(NCC + NB) * sizeof(int), stream);

  k_mask<<<2048, 256, 0, stream>>>(msk, W2l, W2r, wt);
  k_binA<<<(N_EDGES + 2047) / 2048, 256, 0, stream>>>(src, dst, curA, bufA);
  k_binB<<<NCC * BPC, 256, 0, stream>>>(bufA, curA, cur, buf);
  k_bscan<<<1, 1024, 0, stream>>>(cur, bbase);
  k_bfill<<<NB, 256, 0, stream>>>(buf, cur, bbase, deg, offs, eidx);

  k_transform1<<<1024, 256, 0, stream>>>(x, W1l, W1r, xlbh, xr);
  k_gather1<<<2 * GHB, 256, 0, stream>>>(xlbh, xr, offs, deg, eidx, b1, msk, hpbh);
  k_gather2<<<2 * GHB, 256, 0, stream>>>(hpbh, offs, deg, eidx, aggh);
  k_out2<<<(N_NODES + 255) / 256, 256, 0, stream>>>(hpbh, aggh, W2lT, b2, W2rT, msk + M1W, out);
}

// Round 12
// 281.415 us; speedup vs baseline: 1.1620x; 1.1620x over previous
//
#include <hip/hip_runtime.h>

#define N_NODES 100000
#define N_EDGES 1600000
#define NPB 32                       // nodes per bucket (dst >> 5)
#define NB (N_NODES / NPB)           // 3125 buckets
#define CAP 704                      // slots per bucket (mean 512 + 8.5 sigma)
#define NCC 49                       // coarse cells (dst >> 11)
#define CAPA 34816                   // slots per coarse cell (mean 32768 + 11 sigma)
#define NFB 64                       // fine buckets per coarse cell
#define BPC 16                       // blocks per cell in pass B
#define M1W 50000                    // mask1 u64 words (N*32/64)
#define M2W 100000                   // mask2 u64 words (N*64/64)

typedef float v2f __attribute__((ext_vector_type(2)));

// ---------------- JAX threefry2x32 (partitionable scheme) ----------------
struct U2 { unsigned a, b; };

__host__ __device__ constexpr U2 tf2x32(unsigned k0, unsigned k1, unsigned c0, unsigned c1) {
  unsigned ks2 = k0 ^ k1 ^ 0x1BD11BDAu;
  unsigned x0 = c0 + k0, x1 = c1 + k1;
#define TFR(r) { x0 += x1; x1 = (x1 << (r)) | (x1 >> (32 - (r))); x1 ^= x0; }
  TFR(13) TFR(15) TFR(26) TFR(6)
  x0 += k1;  x1 += ks2 + 1u;
  TFR(17) TFR(29) TFR(16) TFR(24)
  x0 += ks2; x1 += k0 + 2u;
  TFR(13) TFR(15) TFR(26) TFR(6)
  x0 += k0;  x1 += k1 + 3u;
  TFR(17) TFR(29) TFR(16) TFR(24)
  x0 += k1;  x1 += ks2 + 4u;
  TFR(13) TFR(15) TFR(26) TFR(6)
  x0 += ks2; x1 += k0 + 5u;
#undef TFR
  return U2{x0, x1};
}

constexpr U2 DK0 = tf2x32(0u, 42u, 0u, 0u);
constexpr U2 DK1 = tf2x32(0u, 42u, 0u, 1u);

__device__ __forceinline__ bool keep_bit(unsigned k0, unsigned k1, unsigned j) {
  U2 w = tf2x32(k0, k1, 0u, j);
  return ((w.a ^ w.b) >> 31) == 0u;
}

// bf16 storage helpers (RNE pack, shift unpack)
__device__ __forceinline__ unsigned short f2bf(float f) {
  unsigned u = __float_as_uint(f);
  u += 0x7FFFu + ((u >> 16) & 1u);
  return (unsigned short)(u >> 16);
}
// unpack uint32 (2 bf16) -> v2f
__device__ __forceinline__ v2f up2(unsigned r) {
  v2f v;
  v.x = __uint_as_float(r << 16);
  v.y = __uint_as_float(r & 0xFFFF0000u);
  return v;
}

// ------ Mask precompute: both dropout masks, 1 bit/element ---------------
// Pure function of constants. Removes the ~72-VALU-op threefry chain from
// the latency-bound k_gather1 / k_out epilogues (each wave: one uniform
// mask-word load instead). Word layout: word w covers j = w*64 + lane,
// which matches gather1 (word = pair) and k_out (word = wid) exactly.
__global__ __launch_bounds__(256) void k_mask(unsigned long long* __restrict__ msk) {
  int w = (int)((blockIdx.x * blockDim.x + threadIdx.x) >> 6);
  int lane = threadIdx.x & 63;
  int nw = (int)((gridDim.x * blockDim.x) >> 6);
  for (; w < M1W + M2W; w += nw) {
    unsigned k0, k1, j;
    if (w < M1W) { k0 = DK0.a; k1 = DK0.b; j = (unsigned)w * 64u + (unsigned)lane; }
    else { k0 = DK1.a; k1 = DK1.b; j = (unsigned)(w - M1W) * 64u + (unsigned)lane; }
    unsigned long long bits = __ballot(keep_bit(k0, k1, j));
    if (lane == 0) msk[w] = bits;
  }
}

// ------ Kernel A: xl = bf16(x@W1_l), xr = x@W1_r ------------------------
// Persistent grid-stride waves (round-1 verified structure).
__global__ __launch_bounds__(256, 4) void k_transform1(
    const float* __restrict__ x, const float* __restrict__ Wl,
    const float* __restrict__ Wr, unsigned short* __restrict__ xlb,
    float* __restrict__ xr) {
  __shared__ __align__(16) float rv[4][64];
  int lane = threadIdx.x & 63;
  int wv = (threadIdx.x >> 6) & 3;
  const float* W = (lane < 32) ? Wl : Wr;
  int c = lane & 31;
  float w[64];
#pragma unroll
  for (int k = 0; k < 64; ++k) w[k] = W[k * 32 + c];
  int wid0 = (int)((blockIdx.x * blockDim.x + threadIdx.x) >> 6);
  int wstride = (int)((gridDim.x * blockDim.x) >> 6);
  for (int wid = wid0; wid < N_NODES; wid += wstride) {
    float xv = x[wid * 64 + lane];
    asm volatile("s_waitcnt lgkmcnt(0)" ::: "memory");   // WAR: prior reads done
    rv[wv][lane] = xv;
    asm volatile("s_waitcnt lgkmcnt(0)" ::: "memory");   // same-wave LDS drain
    v2f s0 = {0.f, 0.f}, s1 = {0.f, 0.f};
#pragma unroll
    for (int k = 0; k < 64; k += 4) {
      float4 r = *(const float4*)&rv[wv][k];
      v2f w0; w0.x = w[k + 0]; w0.y = w[k + 1];
      v2f w1; w1.x = w[k + 2]; w1.y = w[k + 3];
      v2f p0; p0.x = r.x; p0.y = r.y;
      v2f p1; p1.x = r.z; p1.y = r.w;
      s0 += p0 * w0;                   // v_pk_fma_f32
      s1 += p1 * w1;
    }
    float s = (s0.x + s0.y) + (s1.x + s1.y);
    if (lane < 32) xlb[wid * 32 + c] = f2bf(s);
    else           xr[wid * 32 + c] = s;
  }
}

// ------ Pass A: LDS-staged partition by coarse cell (dst>>11), 49 cells ---
__global__ __launch_bounds__(256) void k_binA(
    const int* __restrict__ src, const int* __restrict__ dst,
    int* __restrict__ curA, unsigned* __restrict__ bufA) {
  __shared__ int hist[NCC];
  __shared__ int offsL[NCC + 1];
  __shared__ int baseL[NCC];
  __shared__ int place[NCC];
  __shared__ unsigned stag[2048];
  __shared__ unsigned char cellb[2048];
  int t = threadIdx.x;
  for (long long start = (long long)blockIdx.x * 2048; start < N_EDGES;
       start += (long long)gridDim.x * 2048) {
    int n = (int)min((long long)2048, (long long)N_EDGES - start);
    for (int i = t; i < NCC; i += 256) hist[i] = 0;
    __syncthreads();
    unsigned pv[8]; int pc[8];
#pragma unroll
    for (int i = 0; i < 8; ++i) {
      int idx = t + i * 256;
      if (idx < n) {
        int d = dst[start + idx];
        int s = src[start + idx];
        int cc = d >> 11;
        pc[i] = cc;
        pv[i] = (unsigned)s | ((unsigned)(d & 2047) << 17);
        atomicAdd(&hist[cc], 1);
      } else pc[i] = -1;
    }
    __syncthreads();
    if (t < 64) {
      int lane = t;
      int v = (lane < NCC) ? hist[lane] : 0;
      int x = v;
#pragma unroll
      for (int o = 1; o < 64; o <<= 1) {
        int y = __shfl_up(x, o, 64);
        if (lane >= o) x += y;
      }
      if (lane < NCC) {
        offsL[lane] = x - v;
        place[lane] = 0;
        if (v > 0) baseL[lane] = atomicAdd(&curA[lane], v);
      }
      if (lane == NCC - 1) offsL[NCC] = x;
    }
    __syncthreads();
#pragma unroll
    for (int i = 0; i < 8; ++i) {
      if (pc[i] >= 0) {
        int p = atomicAdd(&place[pc[i]], 1);
        int sl = offsL[pc[i]] + p;
        stag[sl] = pv[i];
        cellb[sl] = (unsigned char)pc[i];
      }
    }
    __syncthreads();
    for (int s2 = t; s2 < n; s2 += 256) {     // coalesced copy-out, no search
      int cell = cellb[s2];
      int pos = baseL[cell] + (s2 - offsL[cell]);
      if (pos < CAPA) bufA[(size_t)cell * CAPA + pos] = stag[s2];
    }
    __syncthreads();
  }
}

// ------ Pass B: refine each coarse cell into 64 fine buckets -------------
__global__ __launch_bounds__(256) void k_binB(
    const unsigned* __restrict__ bufA, const int* __restrict__ curA,
    int* __restrict__ cur, unsigned* __restrict__ buf) {
  __shared__ int hist[NFB];
  __shared__ int offsL[NFB + 1];
  __shared__ int baseL[NFB];
  __shared__ int place[NFB];
  __shared__ unsigned stag[2048];
  __shared__ unsigned char cellb[2048];
  int cellc = blockIdx.x / BPC;
  int slice = blockIdx.x % BPC;
  int t = threadIdx.x;
  int cnt = min(curA[cellc], CAPA);
  const unsigned* in = bufA + (size_t)cellc * CAPA;
  for (int start = slice * 2048; start < cnt; start += BPC * 2048) {
    int n = min(2048, cnt - start);
    for (int i = t; i < NFB; i += 256) hist[i] = 0;
    __syncthreads();
    unsigned pv[8]; int pb[8];
#pragma unroll
    for (int i = 0; i < 8; ++i) {
      int idx = t + i * 256;
      if (idx < n) {
        unsigned w = in[start + idx];
        int dlow = (int)(w >> 17);
        int fb = dlow >> 5;
        pb[i] = fb;
        pv[i] = (w & 0x1FFFFu) | ((unsigned)(dlow & 31) << 17);
        atomicAdd(&hist[fb], 1);
      } else pb[i] = -1;
    }
    __syncthreads();
    if (t < 64) {
      int lane = t;
      int v = hist[lane];
      int x = v;
#pragma unroll
      for (int o = 1; o < 64; o <<= 1) {
        int y = __shfl_up(x, o, 64);
        if (lane >= o) x += y;
      }
      offsL[lane] = x - v;
      place[lane] = 0;
      if (v > 0) baseL[lane] = atomicAdd(&cur[cellc * NFB + lane], v);
      if (lane == 63) offsL[NFB] = x;
    }
    __syncthreads();
#pragma unroll
    for (int i = 0; i < 8; ++i) {
      if (pb[i] >= 0) {
        int p = atomicAdd(&place[pb[i]], 1);
        int sl = offsL[pb[i]] + p;
        stag[sl] = pv[i];
        cellb[sl] = (unsigned char)pb[i];
      }
    }
    __syncthreads();
    for (int s2 = t; s2 < n; s2 += 256) {
      int fb = cellb[s2];
      int pos = baseL[fb] + (s2 - offsL[fb]);
      if (pos < CAP) buf[(size_t)(cellc * NFB + fb) * CAP + pos] = stag[s2];
    }
    __syncthreads();
  }
}

// --------- single-block exclusive scan of bucket totals -> bbase ----------
__global__ __launch_bounds__(1024) void k_bscan(
    const int* __restrict__ cur, int* __restrict__ bbase) {
  __shared__ int warp_sums[16];
  __shared__ int s_running;
  int t = threadIdx.x;
  int lane = t & 63, w = t >> 6;
  if (t == 0) s_running = 0;
  __syncthreads();
  for (int base = 0; base < NB; base += 1024) {
    int i = base + t;
    int v = (i < NB) ? min(cur[i], CAP) : 0;
    int x = v;
#pragma unroll
    for (int o = 1; o < 64; o <<= 1) {
      int y = __shfl_up(x, o, 64);
      if (lane >= o) x += y;
    }
    if (lane == 63) warp_sums[w] = x;
    __syncthreads();
    if (w == 0) {
      int ws = (lane < 16) ? warp_sums[lane] : 0;
#pragma unroll
      for (int o = 1; o < 16; o <<= 1) {
        int y = __shfl_up(ws, o, 64);
        if (lane >= o) ws += y;
      }
      if (lane < 16) warp_sums[lane] = ws;
    }
    __syncthreads();
    int incl = x + (w > 0 ? warp_sums[w - 1] : 0);
    int excl = s_running + incl - v;
    if (i < NB) bbase[i] = excl;
    __syncthreads();
    if (t == 1023) s_running += incl;
    __syncthreads();
  }
}

// ------ block per bucket: LDS-staged count + prefix, dense CSR fill -------
__global__ __launch_bounds__(256) void k_bfill(
    const unsigned* __restrict__ buf, const int* __restrict__ cur,
    const int* __restrict__ bbase, int* __restrict__ deg,
    int* __restrict__ offs, int* __restrict__ eidx) {
  __shared__ int ncnt[NPB];
  __shared__ int ncur[NPB];
  __shared__ unsigned sbuf[CAP];
  int b = blockIdx.x, t = threadIdx.x;
  if (t < NPB) ncnt[t] = 0;
  __syncthreads();
  int nb = min(cur[b], CAP);
  const unsigned* bb = buf + (size_t)b * CAP;
  for (int slot = t; slot < nb; slot += 256) {
    unsigned w = bb[slot];
    sbuf[slot] = w;
    atomicAdd(&ncnt[w >> 17], 1);
  }
  __syncthreads();
  if (t < 64) {
    int lane = t;
    int c = (lane < NPB) ? ncnt[lane] : 0;
    int x = c;
#pragma unroll
    for (int o = 1; o < 32; o <<= 1) {
      int y = __shfl_up(x, o, 64);
      if (lane >= o) x += y;
    }
    if (lane < NPB) {
      int excl = x - c;
      ncur[lane] = excl;
      int gn = b * NPB + lane;
      deg[gn] = c;
      offs[gn] = bbase[b] + excl;
    }
  }
  __syncthreads();
  int base = bbase[b];
  for (int slot = t; slot < nb; slot += 256) {
    unsigned w = sbuf[slot];
    int p = atomicAdd(&ncur[w >> 17], 1);
    eidx[base + p] = (int)(w & 0x1FFFF);
  }
}

// ---- Gather layer 1: TWO nodes per wave (round-1 verified) --------------
// Dropout bit now from the precomputed mask word (word index == pair,
// bit == lane), replacing the 72-op threefry chain in the epilogue.
__global__ __launch_bounds__(256) void k_gather1(
    const unsigned short* __restrict__ xlb, const float* __restrict__ xr,
    const int* __restrict__ offs, const int* __restrict__ deg,
    const int* __restrict__ eidx, const float* __restrict__ b1,
    const unsigned long long* __restrict__ msk1,
    unsigned short* __restrict__ hpb) {
  int pair = (int)((blockIdx.x * blockDim.x + threadIdx.x) >> 6);
  int lane = threadIdx.x & 63;
  int half = lane >> 5;
  int node = pair * 2 + half;
  if (node >= N_NODES) return;
  int g = (lane >> 3) & 3;             // edge group within half: 0..3
  int ch = lane & 7;                   // 8B chunk: 0..7
  int c32 = lane & 31;
  int off = offs[node];
  int dg = deg[node];
  // hoisted tail operands (in flight during gather)
  float xr_v = xr[node * 32 + c32];
  float b1_v = b1[c32];
  unsigned long long mw = msk1[pair];  // wave-uniform mask word
  const uint2* x2 = (const uint2*)xlb;
  v2f acc01 = {0.f, 0.f}, acc23 = {0.f, 0.f};
  int k = 0;
  for (; k + 8 <= dg; k += 8) {        // 8 edges/node/iter, 2 idx + 2 row loads
    int s0 = eidx[off + k + g];
    int s1 = eidx[off + k + 4 + g];
    uint2 r0 = x2[s0 * 8 + ch];
    uint2 r1 = x2[s1 * 8 + ch];
    acc01 += up2(r0.x); acc23 += up2(r0.y);
    acc01 += up2(r1.x); acc23 += up2(r1.y);
  }
  for (; k < dg; k += 4) {
    if (k + g < dg) {
      int s = eidx[off + k + g];
      uint2 r = x2[s * 8 + ch];
      acc01 += up2(r.x); acc23 += up2(r.y);
    }
  }
  float a0 = acc01.x, a1 = acc01.y, a2 = acc23.x, a3 = acc23.y;
  // reduce across the 4 groups (lane bits 3,4) — intra-half
  a0 += __shfl_xor(a0, 8, 64); a0 += __shfl_xor(a0, 16, 64);
  a1 += __shfl_xor(a1, 8, 64); a1 += __shfl_xor(a1, 16, 64);
  a2 += __shfl_xor(a2, 8, 64); a2 += __shfl_xor(a2, 16, 64);
  a3 += __shfl_xor(a3, 8, 64); a3 += __shfl_xor(a3, 16, 64);
  // redistribute: lane wants col c32 = chunk*4 + sub; source lane in same half
  int chunk = c32 >> 2, sub = lane & 3;
  int srcl = (half << 5) + chunk;      // (srcl & 7) == chunk, group 0 — reduced
  float t0 = __shfl(a0, srcl, 64);
  float t1 = __shfl(a1, srcl, 64);
  float t2 = __shfl(a2, srcl, 64);
  float t3 = __shfl(a3, srcl, 64);
  float val = (sub == 0) ? t0 : (sub == 1) ? t1 : (sub == 2) ? t2 : t3;
  float inv = 1.0f / fmaxf((float)dg, 1.0f);
  int j = node * 32 + c32;
  float v = val * inv + b1_v + xr_v;
  v = (v > 0.f) ? v : 0.01f * v;
  float h = ((mw >> lane) & 1ull) ? 2.0f * v : 0.0f;
  hpb[j] = f2bf(h);                    // full-wave 128B contiguous store
}

// ---- Gather layer 2 + LDS-broadcast GEMM + dropout (mask) + L2 norm ----
// Round-1 verified fused structure; threefry replaced by mask word
// (word == wid, bit == lane).
__global__ __launch_bounds__(256) void k_out(
    const unsigned short* __restrict__ hpb, const int* __restrict__ offs,
    const int* __restrict__ deg, const int* __restrict__ eidx,
    const float* __restrict__ W2l, const float* __restrict__ b2,
    const float* __restrict__ W2r, const unsigned long long* __restrict__ msk2,
    float* __restrict__ out) {
  __shared__ __align__(16) float rv[4][64];
  int wid = (int)((blockIdx.x * blockDim.x + threadIdx.x) >> 6);
  int lane = threadIdx.x & 63;
  int wv = (threadIdx.x >> 6) & 3;
  if (wid >= N_NODES) return;
  int g = lane >> 3, ch = lane & 7;
  int off = offs[wid];
  int dg = deg[wid];
  const uint2* h2 = (const uint2*)hpb;
  // hoisted: own hp-row chunk (one 64B line/wave) + bias + mask word
  uint2 own = h2[wid * 8 + ch];
  float bias = b2[lane];
  unsigned long long mw = msk2[wid];
  v2f acc01 = {0.f, 0.f}, acc23 = {0.f, 0.f};
  int k = 0;
  for (; k + 16 <= dg; k += 16) {
    int s0 = eidx[off + k + g];
    int s1 = eidx[off + k + 8 + g];
    uint2 r0 = h2[s0 * 8 + ch];
    uint2 r1 = h2[s1 * 8 + ch];
    acc01 += up2(r0.x); acc23 += up2(r0.y);
    acc01 += up2(r1.x); acc23 += up2(r1.y);
  }
  for (; k < dg; k += 8) {
    if (k + g < dg) {
      int s = eidx[off + k + g];
      uint2 r = h2[s * 8 + ch];
      acc01 += up2(r.x); acc23 += up2(r.y);
    }
  }
  float a0 = acc01.x, a1 = acc01.y, a2 = acc23.x, a3 = acc23.y;
  a0 += __shfl_xor(a0, 8, 64); a0 += __shfl_xor(a0, 16, 64); a0 += __shfl_xor(a0, 32, 64);
  a1 += __shfl_xor(a1, 8, 64); a1 += __shfl_xor(a1, 16, 64); a1 += __shfl_xor(a1, 32, 64);
  a2 += __shfl_xor(a2, 8, 64); a2 += __shfl_xor(a2, 16, 64); a2 += __shfl_xor(a2, 32, 64);
  a3 += __shfl_xor(a3, 8, 64); a3 += __shfl_xor(a3, 16, 64); a3 += __shfl_xor(a3, 32, 64);
  float inv = 1.0f / fmaxf((float)dg, 1.0f);
  if (lane < 8) {                     // mean-agg row, cols 4*lane..4*lane+3
    float4 v;
    v.x = a0 * inv; v.y = a1 * inv; v.z = a2 * inv; v.w = a3 * inv;
    *(float4*)&rv[wv][lane * 4] = v;
  } else if (lane < 16) {             // own hp row (ch == lane-8 here)
    float4 v;
    v.x = __uint_as_float(own.x << 16);
    v.y = __uint_as_float(own.x & 0xFFFF0000u);
    v.z = __uint_as_float(own.y << 16);
    v.w = __uint_as_float(own.y & 0xFFFF0000u);
    *(float4*)&rv[wv][32 + (lane - 8) * 4] = v;
  }
  asm volatile("s_waitcnt lgkmcnt(0)" ::: "memory");   // same-wave LDS drain
  v2f sa = {0.f, 0.f}, sb = {0.f, 0.f};
#pragma unroll
  for (int kk = 0; kk < 32; kk += 4) {
    float4 r1 = *(const float4*)&rv[wv][kk];
    float4 r2 = *(const float4*)&rv[wv][32 + kk];
    v2f w0; w0.x = W2l[(kk + 0) * 64 + lane]; w0.y = W2l[(kk + 1) * 64 + lane];
    v2f w1; w1.x = W2l[(kk + 2) * 64 + lane]; w1.y = W2l[(kk + 3) * 64 + lane];
    v2f u0; u0.x = W2r[(kk + 0) * 64 + lane]; u0.y = W2r[(kk + 1) * 64 + lane];
    v2f u1; u1.x = W2r[(kk + 2) * 64 + lane]; u1.y = W2r[(kk + 3) * 64 + lane];
    v2f p0; p0.x = r1.x; p0.y = r1.y;
    v2f p1; p1.x = r1.z; p1.y = r1.w;
    v2f q0; q0.x = r2.x; q0.y = r2.y;
    v2f q1; q1.x = r2.z; q1.y = r2.w;
    sa += p0 * w0;  sa += p1 * w1;    // v_pk_fma_f32
    sb += q0 * u0;  sb += q1 * u1;
  }
  float v = (sa.x + sa.y) + (sb.x + sb.y) + bias;
  float d = ((mw >> lane) & 1ull) ? 2.0f * v : 0.0f;
  float ss = d * d;
#pragma unroll
  for (int o = 32; o > 0; o >>= 1) ss += __shfl_xor(ss, o, 64);
  float scale = 1.0f / fmaxf(sqrtf(ss), 1e-12f);
  out[(size_t)wid * 64 + lane] = d * scale;
}

// --------------------------------------------------------------------------
extern "C" void kernel_launch(void* const* d_in, const int* in_sizes, int n_in,
                              void* d_out, int out_size, void* d_ws, size_t ws_size,
                              hipStream_t stream) {
  const float* x   = (const float*)d_in[0];
  const int*   ei  = (const int*)d_in[1];
  const float* W1l = (const float*)d_in[2];
  const float* b1  = (const float*)d_in[3];
  const float* W1r = (const float*)d_in[4];
  const float* W2l = (const float*)d_in[5];
  const float* b2  = (const float*)d_in[6];
  const float* W2r = (const float*)d_in[7];
  float* out = (float*)d_out;

  const int* src = ei;            // edge_index[0]
  const int* dst = ei + N_EDGES;  // edge_index[1]

  const size_t F32 = (size_t)N_NODES * 32;
  char* w = (char*)d_ws;
  // region 1 (12.8 MB): bufA (passes A/B) then xr (transform onward)
  unsigned* bufA = (unsigned*)w;                 // 49*34816*4 = 6.8 MB
  float* xr      = (float*)w;                    // 12.8 MB (bufA dead by then)
  w += F32 * sizeof(float);
  // region 2 (12.8 MB): buf (passes B/bfill) then xlb+hpb (transform onward)
  unsigned* buf  = (unsigned*)w;                 // 3125*704*4 = 8.8 MB
  unsigned short* xlb = (unsigned short*)w;      // 6.4 MB
  unsigned short* hpb = xlb + F32;               // 6.4 MB (buf dead by then)
  w += F32 * 2 * sizeof(unsigned short);
  int* curA  = (int*)w; w += NCC * sizeof(int);
  int* cur   = (int*)w; w += NB * sizeof(int);
  int* bbase = (int*)w; w += NB * sizeof(int);
  int* deg   = (int*)w; w += N_NODES * sizeof(int);
  int* offs  = (int*)w; w += N_NODES * sizeof(int);
  int* eidx  = (int*)w; w += (size_t)N_EDGES * sizeof(int);   // 6.4 MB (dense)
  unsigned long long* msk = (unsigned long long*)w;           // 1.2 MB masks

  hipMemsetAsync(curA, 0, (size_t)(NCC + NB) * sizeof(int), stream);

  k_mask<<<2048, 256, 0, stream>>>(msk);
  k_binA<<<(N_EDGES + 2047) / 2048, 256, 0, stream>>>(src, dst, curA, bufA);
  k_binB<<<NCC * BPC, 256, 0, stream>>>(bufA, curA, cur, buf);
  k_bscan<<<1, 1024, 0, stream>>>(cur, bbase);
  k_bfill<<<NB, 256, 0, stream>>>(buf, cur, bbase, deg, offs, eidx);

  k_transform1<<<1024, 256, 0, stream>>>(x, W1l, W1r, xlb, xr);
  k_gather1<<<(N_NODES / 2 + 3) / 4, 256, 0, stream>>>(xlb, xr, offs, deg, eidx, b1, msk, hpb);
  k_out<<<(N_NODES + 3) / 4, 256, 0, stream>>>(hpb, offs, deg, eidx, W2l, b2, W2r, msk + M1W, out);
}

// Round 13
// 252.328 us; speedup vs baseline: 1.2959x; 1.1153x over previous
//
#include <hip/hip_runtime.h>

#define N_NODES 100000
#define N_EDGES 1600000
#define NPB 32                       // nodes per bucket (dst >> 5)
#define NB (N_NODES / NPB)           // 3125 buckets
#define CAP 704                      // slots per bucket (mean 512 + 8.5 sigma)
#define NCC 49                       // coarse cells (dst >> 11)
#define CAPA 34816                   // slots per coarse cell (mean 32768 + 11 sigma)
#define NFB 64                       // fine buckets per coarse cell
#define BPC 16                       // blocks per cell in pass B

typedef float v2f __attribute__((ext_vector_type(2)));

// ---------------- JAX threefry2x32 (partitionable scheme) ----------------
struct U2 { unsigned a, b; };

__host__ __device__ constexpr U2 tf2x32(unsigned k0, unsigned k1, unsigned c0, unsigned c1) {
  unsigned ks2 = k0 ^ k1 ^ 0x1BD11BDAu;
  unsigned x0 = c0 + k0, x1 = c1 + k1;
#define TFR(r) { x0 += x1; x1 = (x1 << (r)) | (x1 >> (32 - (r))); x1 ^= x0; }
  TFR(13) TFR(15) TFR(26) TFR(6)
  x0 += k1;  x1 += ks2 + 1u;
  TFR(17) TFR(29) TFR(16) TFR(24)
  x0 += ks2; x1 += k0 + 2u;
  TFR(13) TFR(15) TFR(26) TFR(6)
  x0 += k0;  x1 += k1 + 3u;
  TFR(17) TFR(29) TFR(16) TFR(24)
  x0 += k1;  x1 += ks2 + 4u;
  TFR(13) TFR(15) TFR(26) TFR(6)
  x0 += ks2; x1 += k0 + 5u;
#undef TFR
  return U2{x0, x1};
}

constexpr U2 DK0 = tf2x32(0u, 42u, 0u, 0u);
constexpr U2 DK1 = tf2x32(0u, 42u, 0u, 1u);

__device__ __forceinline__ bool keep_bit(unsigned k0, unsigned k1, unsigned j) {
  U2 w = tf2x32(k0, k1, 0u, j);
  return ((w.a ^ w.b) >> 31) == 0u;
}

// bf16 storage helpers (RNE pack, shift unpack)
__device__ __forceinline__ unsigned short f2bf(float f) {
  unsigned u = __float_as_uint(f);
  u += 0x7FFFu + ((u >> 16) & 1u);
  return (unsigned short)(u >> 16);
}
// unpack uint32 (2 bf16) -> v2f
__device__ __forceinline__ v2f up2(unsigned r) {
  v2f v;
  v.x = __uint_as_float(r << 16);
  v.y = __uint_as_float(r & 0xFFFF0000u);
  return v;
}

// ------ Kernel A: xl = bf16(x@W1_l), xr = x@W1_r ------------------------
// Persistent grid-stride waves (round-1 verified structure).
__global__ __launch_bounds__(256, 4) void k_transform1(
    const float* __restrict__ x, const float* __restrict__ Wl,
    const float* __restrict__ Wr, unsigned short* __restrict__ xlb,
    float* __restrict__ xr) {
  __shared__ __align__(16) float rv[4][64];
  int lane = threadIdx.x & 63;
  int wv = (threadIdx.x >> 6) & 3;
  const float* W = (lane < 32) ? Wl : Wr;
  int c = lane & 31;
  float w[64];
#pragma unroll
  for (int k = 0; k < 64; ++k) w[k] = W[k * 32 + c];
  int wid0 = (int)((blockIdx.x * blockDim.x + threadIdx.x) >> 6);
  int wstride = (int)((gridDim.x * blockDim.x) >> 6);
  for (int wid = wid0; wid < N_NODES; wid += wstride) {
    float xv = x[wid * 64 + lane];
    asm volatile("s_waitcnt lgkmcnt(0)" ::: "memory");   // WAR: prior reads done
    rv[wv][lane] = xv;
    asm volatile("s_waitcnt lgkmcnt(0)" ::: "memory");   // same-wave LDS drain
    v2f s0 = {0.f, 0.f}, s1 = {0.f, 0.f};
#pragma unroll
    for (int k = 0; k < 64; k += 4) {
      float4 r = *(const float4*)&rv[wv][k];
      v2f w0; w0.x = w[k + 0]; w0.y = w[k + 1];
      v2f w1; w1.x = w[k + 2]; w1.y = w[k + 3];
      v2f p0; p0.x = r.x; p0.y = r.y;
      v2f p1; p1.x = r.z; p1.y = r.w;
      s0 += p0 * w0;                   // v_pk_fma_f32
      s1 += p1 * w1;
    }
    float s = (s0.x + s0.y) + (s1.x + s1.y);
    if (lane < 32) xlb[wid * 32 + c] = f2bf(s);
    else           xr[wid * 32 + c] = s;
  }
}

// ------ Pass A: LDS-staged partition by coarse cell (dst>>11), 49 cells ---
__global__ __launch_bounds__(256) void k_binA(
    const int* __restrict__ src, const int* __restrict__ dst,
    int* __restrict__ curA, unsigned* __restrict__ bufA) {
  __shared__ int hist[NCC];
  __shared__ int offsL[NCC + 1];
  __shared__ int baseL[NCC];
  __shared__ int place[NCC];
  __shared__ unsigned stag[2048];
  __shared__ unsigned char cellb[2048];
  int t = threadIdx.x;
  for (long long start = (long long)blockIdx.x * 2048; start < N_EDGES;
       start += (long long)gridDim.x * 2048) {
    int n = (int)min((long long)2048, (long long)N_EDGES - start);
    for (int i = t; i < NCC; i += 256) hist[i] = 0;
    __syncthreads();
    unsigned pv[8]; int pc[8];
#pragma unroll
    for (int i = 0; i < 8; ++i) {
      int idx = t + i * 256;
      if (idx < n) {
        int d = dst[start + idx];
        int s = src[start + idx];
        int cc = d >> 11;
        pc[i] = cc;
        pv[i] = (unsigned)s | ((unsigned)(d & 2047) << 17);
        atomicAdd(&hist[cc], 1);
      } else pc[i] = -1;
    }
    __syncthreads();
    if (t < 64) {
      int lane = t;
      int v = (lane < NCC) ? hist[lane] : 0;
      int x = v;
#pragma unroll
      for (int o = 1; o < 64; o <<= 1) {
        int y = __shfl_up(x, o, 64);
        if (lane >= o) x += y;
      }
      if (lane < NCC) {
        offsL[lane] = x - v;
        place[lane] = 0;
        if (v > 0) baseL[lane] = atomicAdd(&curA[lane], v);
      }
      if (lane == NCC - 1) offsL[NCC] = x;
    }
    __syncthreads();
#pragma unroll
    for (int i = 0; i < 8; ++i) {
      if (pc[i] >= 0) {
        int p = atomicAdd(&place[pc[i]], 1);
        int sl = offsL[pc[i]] + p;
        stag[sl] = pv[i];
        cellb[sl] = (unsigned char)pc[i];
      }
    }
    __syncthreads();
    for (int s2 = t; s2 < n; s2 += 256) {     // coalesced copy-out, no search
      int cell = cellb[s2];
      int pos = baseL[cell] + (s2 - offsL[cell]);
      if (pos < CAPA) bufA[(size_t)cell * CAPA + pos] = stag[s2];
    }
    __syncthreads();
  }
}

// ------ Pass B: refine each coarse cell into 64 fine buckets -------------
__global__ __launch_bounds__(256) void k_binB(
    const unsigned* __restrict__ bufA, const int* __restrict__ curA,
    int* __restrict__ cur, unsigned* __restrict__ buf) {
  __shared__ int hist[NFB];
  __shared__ int offsL[NFB + 1];
  __shared__ int baseL[NFB];
  __shared__ int place[NFB];
  __shared__ unsigned stag[2048];
  __shared__ unsigned char cellb[2048];
  int cellc = blockIdx.x / BPC;
  int slice = blockIdx.x % BPC;
  int t = threadIdx.x;
  int cnt = min(curA[cellc], CAPA);
  const unsigned* in = bufA + (size_t)cellc * CAPA;
  for (int start = slice * 2048; start < cnt; start += BPC * 2048) {
    int n = min(2048, cnt - start);
    for (int i = t; i < NFB; i += 256) hist[i] = 0;
    __syncthreads();
    unsigned pv[8]; int pb[8];
#pragma unroll
    for (int i = 0; i < 8; ++i) {
      int idx = t + i * 256;
      if (idx < n) {
        unsigned w = in[start + idx];
        int dlow = (int)(w >> 17);
        int fb = dlow >> 5;
        pb[i] = fb;
        pv[i] = (w & 0x1FFFFu) | ((unsigned)(dlow & 31) << 17);
        atomicAdd(&hist[fb], 1);
      } else pb[i] = -1;
    }
    __syncthreads();
    if (t < 64) {
      int lane = t;
      int v = hist[lane];
      int x = v;
#pragma unroll
      for (int o = 1; o < 64; o <<= 1) {
        int y = __shfl_up(x, o, 64);
        if (lane >= o) x += y;
      }
      offsL[lane] = x - v;
      place[lane] = 0;
      if (v > 0) baseL[lane] = atomicAdd(&cur[cellc * NFB + lane], v);
      if (lane == 63) offsL[NFB] = x;
    }
    __syncthreads();
#pragma unroll
    for (int i = 0; i < 8; ++i) {
      if (pb[i] >= 0) {
        int p = atomicAdd(&place[pb[i]], 1);
        int sl = offsL[pb[i]] + p;
        stag[sl] = pv[i];
        cellb[sl] = (unsigned char)pb[i];
      }
    }
    __syncthreads();
    for (int s2 = t; s2 < n; s2 += 256) {
      int fb = cellb[s2];
      int pos = baseL[fb] + (s2 - offsL[fb]);
      if (pos < CAP) buf[(size_t)(cellc * NFB + fb) * CAP + pos] = stag[s2];
    }
    __syncthreads();
  }
}

// --------- single-block exclusive scan of bucket totals -> bbase ----------
__global__ __launch_bounds__(1024) void k_bscan(
    const int* __restrict__ cur, int* __restrict__ bbase) {
  __shared__ int warp_sums[16];
  __shared__ int s_running;
  int t = threadIdx.x;
  int lane = t & 63, w = t >> 6;
  if (t == 0) s_running = 0;
  __syncthreads();
  for (int base = 0; base < NB; base += 1024) {
    int i = base + t;
    int v = (i < NB) ? min(cur[i], CAP) : 0;
    int x = v;
#pragma unroll
    for (int o = 1; o < 64; o <<= 1) {
      int y = __shfl_up(x, o, 64);
      if (lane >= o) x += y;
    }
    if (lane == 63) warp_sums[w] = x;
    __syncthreads();
    if (w == 0) {
      int ws = (lane < 16) ? warp_sums[lane] : 0;
#pragma unroll
      for (int o = 1; o < 16; o <<= 1) {
        int y = __shfl_up(ws, o, 64);
        if (lane >= o) ws += y;
      }
      if (lane < 16) warp_sums[lane] = ws;
    }
    __syncthreads();
    int incl = x + (w > 0 ? warp_sums[w - 1] : 0);
    int excl = s_running + incl - v;
    if (i < NB) bbase[i] = excl;
    __syncthreads();
    if (t == 1023) s_running += incl;
    __syncthreads();
  }
}

// ------ block per bucket: LDS-staged count + prefix, dense CSR fill -------
__global__ __launch_bounds__(256) void k_bfill(
    const unsigned* __restrict__ buf, const int* __restrict__ cur,
    const int* __restrict__ bbase, int* __restrict__ deg,
    int* __restrict__ offs, int* __restrict__ eidx) {
  __shared__ int ncnt[NPB];
  __shared__ int ncur[NPB];
  __shared__ unsigned sbuf[CAP];
  int b = blockIdx.x, t = threadIdx.x;
  if (t < NPB) ncnt[t] = 0;
  __syncthreads();
  int nb = min(cur[b], CAP);
  const unsigned* bb = buf + (size_t)b * CAP;
  for (int slot = t; slot < nb; slot += 256) {
    unsigned w = bb[slot];
    sbuf[slot] = w;
    atomicAdd(&ncnt[w >> 17], 1);
  }
  __syncthreads();
  if (t < 64) {
    int lane = t;
    int c = (lane < NPB) ? ncnt[lane] : 0;
    int x = c;
#pragma unroll
    for (int o = 1; o < 32; o <<= 1) {
      int y = __shfl_up(x, o, 64);
      if (lane >= o) x += y;
    }
    if (lane < NPB) {
      int excl = x - c;
      ncur[lane] = excl;
      int gn = b * NPB + lane;
      deg[gn] = c;
      offs[gn] = bbase[b] + excl;
    }
  }
  __syncthreads();
  int base = bbase[b];
  for (int slot = t; slot < nb; slot += 256) {
    unsigned w = sbuf[slot];
    int p = atomicAdd(&ncur[w >> 17], 1);
    eidx[base + p] = (int)(w & 0x1FFFF);
  }
}

// ---- Gather layer 1: TWO nodes per wave ---------------------------------
// NEW: edge indices preloaded in ONE coalesced 32-lane load per node
// (sidx), distributed via __shfl — removes the serial eidx->row load
// dependency that limited memory-level parallelism. deg>32 (P~3e-5)
// falls back to direct loads.
__global__ __launch_bounds__(256) void k_gather1(
    const unsigned short* __restrict__ xlb, const float* __restrict__ xr,
    const int* __restrict__ offs, const int* __restrict__ deg,
    const int* __restrict__ eidx, const float* __restrict__ b1,
    unsigned short* __restrict__ hpb) {
  int pair = (int)((blockIdx.x * blockDim.x + threadIdx.x) >> 6);
  int lane = threadIdx.x & 63;
  int half = lane >> 5;
  int node = pair * 2 + half;
  if (node >= N_NODES) return;
  int g = (lane >> 3) & 3;             // edge group within half: 0..3
  int ch = lane & 7;                   // 8B chunk: 0..7
  int c32 = lane & 31;
  int off = offs[node];
  int dg = deg[node];
  // hoisted operands, all in flight together
  float xr_v = xr[node * 32 + c32];
  float b1_v = b1[c32];
  int sidx = eidx[(dg > 0) ? (off + min(c32, dg - 1)) : 0];  // 32 idx/node, coalesced
  int hb = half << 5;
  const uint2* x2 = (const uint2*)xlb;
  v2f acc01 = {0.f, 0.f}, acc23 = {0.f, 0.f};
  int kmax = min(dg, 32);
  int k = 0;
  for (; k + 8 <= kmax; k += 8) {      // 8 edges/node/iter, indices via shfl
    int i0 = __shfl(sidx, hb + k + g, 64);
    int i1 = __shfl(sidx, hb + k + 4 + g, 64);
    uint2 r0 = x2[i0 * 8 + ch];
    uint2 r1 = x2[i1 * 8 + ch];
    acc01 += up2(r0.x); acc23 += up2(r0.y);
    acc01 += up2(r1.x); acc23 += up2(r1.y);
  }
  for (; k < kmax; k += 4) {
    int i = __shfl(sidx, hb + min(k + g, kmax - 1), 64);
    if (k + g < kmax) {
      uint2 r = x2[i * 8 + ch];
      acc01 += up2(r.x); acc23 += up2(r.y);
    }
  }
  for (; k < dg; k += 4) {             // deg>32 fallback (rare)
    if (k + g < dg) {
      int s = eidx[off + k + g];
      uint2 r = x2[s * 8 + ch];
      acc01 += up2(r.x); acc23 += up2(r.y);
    }
  }
  float a0 = acc01.x, a1 = acc01.y, a2 = acc23.x, a3 = acc23.y;
  // reduce across the 4 groups (lane bits 3,4) — intra-half
  a0 += __shfl_xor(a0, 8, 64); a0 += __shfl_xor(a0, 16, 64);
  a1 += __shfl_xor(a1, 8, 64); a1 += __shfl_xor(a1, 16, 64);
  a2 += __shfl_xor(a2, 8, 64); a2 += __shfl_xor(a2, 16, 64);
  a3 += __shfl_xor(a3, 8, 64); a3 += __shfl_xor(a3, 16, 64);
  // redistribute: lane wants col c32 = chunk*4 + sub; source lane in same half
  int chunk = c32 >> 2, sub = lane & 3;
  int srcl = hb + chunk;               // (srcl & 7) == chunk, group 0 — reduced
  float t0 = __shfl(a0, srcl, 64);
  float t1 = __shfl(a1, srcl, 64);
  float t2 = __shfl(a2, srcl, 64);
  float t3 = __shfl(a3, srcl, 64);
  float val = (sub == 0) ? t0 : (sub == 1) ? t1 : (sub == 2) ? t2 : t3;
  float inv = 1.0f / fmaxf((float)dg, 1.0f);
  int j = node * 32 + c32;
  float v = val * inv + b1_v + xr_v;
  v = (v > 0.f) ? v : 0.01f * v;
  float h = keep_bit(DK0.a, DK0.b, (unsigned)j) ? 2.0f * v : 0.0f;
  hpb[j] = f2bf(h);                    // full-wave 128B contiguous store
}

// ---- Gather layer 2 + LDS-broadcast GEMM + dropout + L2 norm ------------
// NEW: same shfl-broadcast index preload (64 idx in one coalesced load).
__global__ __launch_bounds__(256) void k_out(
    const unsigned short* __restrict__ hpb, const int* __restrict__ offs,
    const int* __restrict__ deg, const int* __restrict__ eidx,
    const float* __restrict__ W2l, const float* __restrict__ b2,
    const float* __restrict__ W2r, float* __restrict__ out) {
  __shared__ __align__(16) float rv[4][64];
  int wid = (int)((blockIdx.x * blockDim.x + threadIdx.x) >> 6);
  int lane = threadIdx.x & 63;
  int wv = (threadIdx.x >> 6) & 3;
  if (wid >= N_NODES) return;
  int g = lane >> 3, ch = lane & 7;
  int off = offs[wid];
  int dg = deg[wid];
  const uint2* h2 = (const uint2*)hpb;
  // hoisted: own hp-row chunk + bias + all edge indices (one 256B load)
  uint2 own = h2[wid * 8 + ch];
  float bias = b2[lane];
  int sidx = eidx[(dg > 0) ? (off + min(lane, dg - 1)) : 0];
  v2f acc01 = {0.f, 0.f}, acc23 = {0.f, 0.f};
  int kmax = min(dg, 64);
  int k = 0;
  for (; k + 16 <= kmax; k += 16) {
    int i0 = __shfl(sidx, k + g, 64);
    int i1 = __shfl(sidx, k + 8 + g, 64);
    uint2 r0 = h2[i0 * 8 + ch];
    uint2 r1 = h2[i1 * 8 + ch];
    acc01 += up2(r0.x); acc23 += up2(r0.y);
    acc01 += up2(r1.x); acc23 += up2(r1.y);
  }
  for (; k < kmax; k += 8) {
    int i = __shfl(sidx, min(k + g, kmax - 1), 64);
    if (k + g < kmax) {
      uint2 r = h2[i * 8 + ch];
      acc01 += up2(r.x); acc23 += up2(r.y);
    }
  }
  for (; k < dg; k += 8) {             // deg>64 fallback (essentially never)
    if (k + g < dg) {
      int s = eidx[off + k + g];
      uint2 r = h2[s * 8 + ch];
      acc01 += up2(r.x); acc23 += up2(r.y);
    }
  }
  float a0 = acc01.x, a1 = acc01.y, a2 = acc23.x, a3 = acc23.y;
  a0 += __shfl_xor(a0, 8, 64); a0 += __shfl_xor(a0, 16, 64); a0 += __shfl_xor(a0, 32, 64);
  a1 += __shfl_xor(a1, 8, 64); a1 += __shfl_xor(a1, 16, 64); a1 += __shfl_xor(a1, 32, 64);
  a2 += __shfl_xor(a2, 8, 64); a2 += __shfl_xor(a2, 16, 64); a2 += __shfl_xor(a2, 32, 64);
  a3 += __shfl_xor(a3, 8, 64); a3 += __shfl_xor(a3, 16, 64); a3 += __shfl_xor(a3, 32, 64);
  float inv = 1.0f / fmaxf((float)dg, 1.0f);
  if (lane < 8) {                     // mean-agg row, cols 4*lane..4*lane+3
    float4 v;
    v.x = a0 * inv; v.y = a1 * inv; v.z = a2 * inv; v.w = a3 * inv;
    *(float4*)&rv[wv][lane * 4] = v;
  } else if (lane < 16) {             // own hp row (ch == lane-8 here)
    float4 v;
    v.x = __uint_as_float(own.x << 16);
    v.y = __uint_as_float(own.x & 0xFFFF0000u);
    v.z = __uint_as_float(own.y << 16);
    v.w = __uint_as_float(own.y & 0xFFFF0000u);
    *(float4*)&rv[wv][32 + (lane - 8) * 4] = v;
  }
  asm volatile("s_waitcnt lgkmcnt(0)" ::: "memory");   // same-wave LDS drain
  v2f sa = {0.f, 0.f}, sb = {0.f, 0.f};
#pragma unroll
  for (int kk = 0; kk < 32; kk += 4) {
    float4 r1 = *(const float4*)&rv[wv][kk];
    float4 r2 = *(const float4*)&rv[wv][32 + kk];
    v2f w0; w0.x = W2l[(kk + 0) * 64 + lane]; w0.y = W2l[(kk + 1) * 64 + lane];
    v2f w1; w1.x = W2l[(kk + 2) * 64 + lane]; w1.y = W2l[(kk + 3) * 64 + lane];
    v2f u0; u0.x = W2r[(kk + 0) * 64 + lane]; u0.y = W2r[(kk + 1) * 64 + lane];
    v2f u1; u1.x = W2r[(kk + 2) * 64 + lane]; u1.y = W2r[(kk + 3) * 64 + lane];
    v2f p0; p0.x = r1.x; p0.y = r1.y;
    v2f p1; p1.x = r1.z; p1.y = r1.w;
    v2f q0; q0.x = r2.x; q0.y = r2.y;
    v2f q1; q1.x = r2.z; q1.y = r2.w;
    sa += p0 * w0;  sa += p1 * w1;    // v_pk_fma_f32
    sb += q0 * u0;  sb += q1 * u1;
  }
  float v = (sa.x + sa.y) + (sb.x + sb.y) + bias;
  unsigned j = (unsigned)(wid * 64 + lane);
  float d = keep_bit(DK1.a, DK1.b, j) ? 2.0f * v : 0.0f;
  float ss = d * d;
#pragma unroll
  for (int o = 32; o > 0; o >>= 1) ss += __shfl_xor(ss, o, 64);
  float scale = 1.0f / fmaxf(sqrtf(ss), 1e-12f);
  out[j] = d * scale;
}

// --------------------------------------------------------------------------
extern "C" void kernel_launch(void* const* d_in, const int* in_sizes, int n_in,
                              void* d_out, int out_size, void* d_ws, size_t ws_size,
                              hipStream_t stream) {
  const float* x   = (const float*)d_in[0];
  const int*   ei  = (const int*)d_in[1];
  const float* W1l = (const float*)d_in[2];
  const float* b1  = (const float*)d_in[3];
  const float* W1r = (const float*)d_in[4];
  const float* W2l = (const float*)d_in[5];
  const float* b2  = (const float*)d_in[6];
  const float* W2r = (const float*)d_in[7];
  float* out = (float*)d_out;

  const int* src = ei;            // edge_index[0]
  const int* dst = ei + N_EDGES;  // edge_index[1]

  const size_t F32 = (size_t)N_NODES * 32;
  char* w = (char*)d_ws;
  // region 1 (12.8 MB): bufA (passes A/B) then xr (transform onward)
  unsigned* bufA = (unsigned*)w;                 // 49*34816*4 = 6.8 MB
  float* xr      = (float*)w;                    // 12.8 MB (bufA dead by then)
  w += F32 * sizeof(float);
  // region 2 (12.8 MB): buf (passes B/bfill) then xlb+hpb (transform onward)
  unsigned* buf  = (unsigned*)w;                 // 3125*704*4 = 8.8 MB
  unsigned short* xlb = (unsigned short*)w;      // 6.4 MB
  unsigned short* hpb = xlb + F32;               // 6.4 MB (buf dead by then)
  w += F32 * 2 * sizeof(unsigned short);
  int* curA  = (int*)w; w += NCC * sizeof(int);
  int* cur   = (int*)w; w += NB * sizeof(int);
  int* bbase = (int*)w; w += NB * sizeof(int);
  int* deg   = (int*)w; w += N_NODES * sizeof(int);
  int* offs  = (int*)w; w += N_NODES * sizeof(int);
  int* eidx  = (int*)w;                          // 6.4 MB (dense)

  hipMemsetAsync(curA, 0, (size_t)(NCC + NB) * sizeof(int), stream);

  k_binA<<<(N_EDGES + 2047) / 2048, 256, 0, stream>>>(src, dst, curA, bufA);
  k_binB<<<NCC * BPC, 256, 0, stream>>>(bufA, curA, cur, buf);
  k_bscan<<<1, 1024, 0, stream>>>(cur, bbase);
  k_bfill<<<NB, 256, 0, stream>>>(buf, cur, bbase, deg, offs, eidx);

  k_transform1<<<1024, 256, 0, stream>>>(x, W1l, W1r, xlb, xr);
  k_gather1<<<(N_NODES / 2 + 3) / 4, 256, 0, stream>>>(xlb, xr, offs, deg, eidx, b1, hpb);
  k_out<<<(N_NODES + 3) / 4, 256, 0, stream>>>(hpb, offs, deg, eidx, W2l, b2, W2r, out);
}